// Round 4
// baseline (679.169 us; speedup 1.0000x reference)
//
#include <hip/hip_runtime.h>
#include <math.h>

// Problem: B=16384 rows, N=4096 cols.
//   mask = (e == 1.0); e_scaled = e * diag
//   out0 = softmax(where(mask, e_scaled, -inf), axis=-1)   [B*N floats]
//   out1 = e_scaled                                        [B*N floats]
// Memory-bound: 256 MB read + 512 MB write -> ~122 us floor at 6.3 TB/s.

#define NROWS 16384
#define NCOLS 4096
#define BLOCK 256          // 4 waves of 64
#define EPT   (NCOLS / BLOCK)   // 16 elements per thread
#define NEG_SENT -3.0e38f  // finite sentinel instead of -inf (NaN-safe merges)

__global__ __launch_bounds__(BLOCK) void masked_softmax_kernel(
    const float* __restrict__ e,
    const float* __restrict__ diag,
    float* __restrict__ out) {
  const int row  = blockIdx.x;
  const int tid  = threadIdx.x;
  const int wave = tid >> 6;
  const int lane = tid & 63;

  const float* __restrict__ erow = e + (size_t)row * NCOLS;

  // ---- Load 16 e-values + 16 diag-values per thread (float4, coalesced) ----
  float ee[EPT], dd[EPT];
#pragma unroll
  for (int k = 0; k < 4; ++k) {
    const int c = k * (BLOCK * 4) + tid * 4;  // k*1024 + tid*4
    const float4 a = *reinterpret_cast<const float4*>(erow + c);
    const float4 b = *reinterpret_cast<const float4*>(diag + c);
    ee[4 * k + 0] = a.x; ee[4 * k + 1] = a.y; ee[4 * k + 2] = a.z; ee[4 * k + 3] = a.w;
    dd[4 * k + 0] = b.x; dd[4 * k + 1] = b.y; dd[4 * k + 2] = b.z; dd[4 * k + 3] = b.w;
  }

  // ---- Thread-local max over available entries ----
  float m_loc = NEG_SENT;
#pragma unroll
  for (int i = 0; i < EPT; ++i) {
    const float v = (ee[i] == 1.0f) ? dd[i] : NEG_SENT;
    m_loc = fmaxf(m_loc, v);
  }

  // ---- Thread-local exp values + partial sum ----
  float p[EPT];
  float s = 0.0f;
#pragma unroll
  for (int i = 0; i < EPT; ++i) {
    const float pe = (ee[i] == 1.0f) ? __expf(dd[i] - m_loc) : 0.0f;
    p[i] = pe;
    s += pe;
  }

  // ---- Wave (64-lane) online-softmax merge via shfl_xor butterfly ----
  float mr = m_loc, sr = s;
#pragma unroll
  for (int off = 1; off < 64; off <<= 1) {
    const float mo = __shfl_xor(mr, off);
    const float so = __shfl_xor(sr, off);
    const float nm = fmaxf(mr, mo);
    sr = sr * __expf(mr - nm) + so * __expf(mo - nm);
    mr = nm;
  }

  // ---- Cross-wave merge through LDS (4 waves) ----
  __shared__ float sm[4], ss[4];
  if (lane == 0) { sm[wave] = mr; ss[wave] = sr; }
  __syncthreads();
  float M = sm[0], S = ss[0];
#pragma unroll
  for (int w = 1; w < 4; ++w) {
    const float mo = sm[w], so = ss[w];
    const float nm = fmaxf(M, mo);
    S = S * __expf(M - nm) + so * __expf(mo - nm);
    M = nm;
  }

  // ---- Rescale register-resident exps and write both outputs (float4) ----
  const float scale = __expf(m_loc - M) / S;  // exp(-huge)=0 when thread empty

  float* __restrict__ o0 = out + (size_t)row * NCOLS;                          // softmax
  float* __restrict__ o1 = out + (size_t)NROWS * NCOLS + (size_t)row * NCOLS;  // e_scaled
#pragma unroll
  for (int k = 0; k < 4; ++k) {
    const int c = k * (BLOCK * 4) + tid * 4;
    float4 r0, r1;
    r0.x = p[4 * k + 0] * scale; r0.y = p[4 * k + 1] * scale;
    r0.z = p[4 * k + 2] * scale; r0.w = p[4 * k + 3] * scale;
    r1.x = ee[4 * k + 0] * dd[4 * k + 0]; r1.y = ee[4 * k + 1] * dd[4 * k + 1];
    r1.z = ee[4 * k + 2] * dd[4 * k + 2]; r1.w = ee[4 * k + 3] * dd[4 * k + 3];
    *reinterpret_cast<float4*>(o0 + c) = r0;
    *reinterpret_cast<float4*>(o1 + c) = r1;
  }
}

extern "C" void kernel_launch(void* const* d_in, const int* in_sizes, int n_in,
                              void* d_out, int out_size, void* d_ws, size_t ws_size,
                              hipStream_t stream) {
  const float* e    = (const float*)d_in[0];
  const float* diag = (const float*)d_in[1];
  float* out        = (float*)d_out;
  masked_softmax_kernel<<<NROWS, BLOCK, 0, stream>>>(e, diag, out);
}

// Round 6
// 671.910 us; speedup vs baseline: 1.0108x; 1.0108x over previous
//
#include <hip/hip_runtime.h>
#include <math.h>

// B=16384 rows, N=4096 cols.
//   mask = (e == 1.0); e_scaled = e * diag
//   out0 = softmax(where(mask, e_scaled, -inf), -1)  [B*N f32]
//   out1 = e_scaled                                  [B*N f32]
// HBM-bound: 256 MB read + 512 MB write -> ~122 us kernel floor @ 6.3 TB/s.
// R4 lesson: dur_us includes harness re-poison/restore (~500 us of fills);
// kernel itself is <334 us (absent from top-5). This round: leaner reduce
// (exp once, two-phase), 33 live regs instead of 48, nontemporal streams.

#define NROWS 16384
#define NCOLS 4096
#define BLOCK 256               // 4 waves of 64
#define EPT   (NCOLS / BLOCK)   // 16 elements per thread
#define NEG_SENT -3.0e38f       // finite sentinel (NaN-safe max merges)

typedef float f32x4 __attribute__((ext_vector_type(4)));

__global__ __launch_bounds__(BLOCK) void masked_softmax_kernel(
    const float* __restrict__ e,
    const float* __restrict__ diag,
    float* __restrict__ out) {
  const int tid  = threadIdx.x;
  const int wave = tid >> 6;
  const int lane = tid & 63;
  const int row  = blockIdx.x;

  const float* __restrict__ erow = e + (size_t)row * NCOLS;

  // ---- Load + fuse: esc = e*diag; mask bit = (e==1). When e==1, the
  // masked logit IS esc (since 1*diag = diag). 16 f32 + 1 mask reg live. ----
  float esc[EPT];
  unsigned msk = 0;
  float m_loc = NEG_SENT;
#pragma unroll
  for (int k = 0; k < 4; ++k) {
    const int c = k * (BLOCK * 4) + tid * 4;
    const f32x4 a = __builtin_nontemporal_load((const f32x4*)(erow + c));
    const f32x4 b = *(const f32x4*)(diag + c);   // cached: reused by all rows
#pragma unroll
    for (int j = 0; j < 4; ++j) {
      const int i = 4 * k + j;
      const float av = a[j];
      const float ev = av * b[j];
      esc[i] = ev;
      const bool on = (av == 1.0f);
      msk |= (unsigned)on << i;
      m_loc = fmaxf(m_loc, on ? ev : NEG_SENT);
    }
  }

  // ---- Phase 1: block max (plain fmax butterfly — no exp on critical path)
#pragma unroll
  for (int off = 32; off >= 1; off >>= 1)
    m_loc = fmaxf(m_loc, __shfl_xor(m_loc, off));

  __shared__ float sm[4], ss[4];
  if (lane == 0) sm[wave] = m_loc;
  __syncthreads();
  const float M = fmaxf(fmaxf(sm[0], sm[1]), fmaxf(sm[2], sm[3]));

  // ---- Phase 2: exp once per element, then sum butterfly ----
  float p[EPT];
  float s = 0.0f;
#pragma unroll
  for (int i = 0; i < EPT; ++i) {
    const float pe = ((msk >> i) & 1u) ? __expf(esc[i] - M) : 0.0f;
    p[i] = pe;
    s += pe;
  }
#pragma unroll
  for (int off = 32; off >= 1; off >>= 1)
    s += __shfl_xor(s, off);
  if (lane == 0) ss[wave] = s;
  __syncthreads();
  const float S = (ss[0] + ss[1]) + (ss[2] + ss[3]);
  const float inv = 1.0f / S;

  // ---- Streamed writes (nontemporal: never re-read, keep L2 for e/diag) ----
  float* __restrict__ o0 = out + (size_t)row * NCOLS;                          // softmax
  float* __restrict__ o1 = out + (size_t)NROWS * NCOLS + (size_t)row * NCOLS;  // e_scaled
#pragma unroll
  for (int k = 0; k < 4; ++k) {
    const int c = k * (BLOCK * 4) + tid * 4;
    f32x4 r0, r1;
#pragma unroll
    for (int j = 0; j < 4; ++j) {
      r0[j] = p[4 * k + j] * inv;
      r1[j] = esc[4 * k + j];
    }
    __builtin_nontemporal_store(r0, (f32x4*)(o0 + c));
    __builtin_nontemporal_store(r1, (f32x4*)(o1 + c));
  }
}

extern "C" void kernel_launch(void* const* d_in, const int* in_sizes, int n_in,
                              void* d_out, int out_size, void* d_ws, size_t ws_size,
                              hipStream_t stream) {
  const float* e    = (const float*)d_in[0];
  const float* diag = (const float*)d_in[1];
  float* out        = (float*)d_out;
  masked_softmax_kernel<<<NROWS, BLOCK, 0, stream>>>(e, diag, out);
}

// Round 10
// 665.261 us; speedup vs baseline: 1.0209x; 1.0100x over previous
//
#include <hip/hip_runtime.h>
#include <math.h>

// B=16384 rows, N=4096 cols.
//   mask = (e == 1.0); e_scaled = e * diag
//   out0 = softmax(where(mask, e_scaled, -inf), -1)  [B*N f32]
//   out1 = e_scaled                                  [B*N f32]
// HBM-bound: 256 MB read + 512 MB write -> ~122 us kernel floor @ 6.3 TB/s.
// Measured dur_us includes ~500 us of harness re-poison/restore traffic;
// kernel-proper ~172 us (R6). R7 change: store o1 (e_scaled) EARLY, inside
// the load loop, so the write stream overlaps the loads + block reduction
// instead of serializing behind them.

#define NROWS 16384
#define NCOLS 4096
#define BLOCK 256               // 4 waves of 64
#define EPT   (NCOLS / BLOCK)   // 16 elements per thread
#define NEG_SENT -3.0e38f       // finite sentinel (NaN-safe max merges)

typedef float f32x4 __attribute__((ext_vector_type(4)));

__global__ __launch_bounds__(BLOCK) void masked_softmax_kernel(
    const float* __restrict__ e,
    const float* __restrict__ diag,
    float* __restrict__ out) {
  const int tid  = threadIdx.x;
  const int wave = tid >> 6;
  const int lane = tid & 63;
  const int row  = blockIdx.x;

  const float* __restrict__ erow = e + (size_t)row * NCOLS;
  float* __restrict__ o0 = out + (size_t)row * NCOLS;                          // softmax
  float* __restrict__ o1 = out + (size_t)NROWS * NCOLS + (size_t)row * NCOLS;  // e_scaled

  // ---- Load + fuse + EARLY o1 store. esc = e*diag; mask bit = (e==1).
  // o1 depends only on the loads, so its stores are issued here, before any
  // barrier: the 512 MB e_scaled write stream flows while other chunks load
  // and while the block reduction runs. ----
  float esc[EPT];
  unsigned msk = 0;
  float m_loc = NEG_SENT;
#pragma unroll
  for (int k = 0; k < 4; ++k) {
    const int c = k * (BLOCK * 4) + tid * 4;
    const f32x4 a = __builtin_nontemporal_load((const f32x4*)(erow + c));
    const f32x4 b = *(const f32x4*)(diag + c);   // cached: reused by all rows
    f32x4 r1;
#pragma unroll
    for (int j = 0; j < 4; ++j) {
      const int i = 4 * k + j;
      const float av = a[j];
      const float ev = av * b[j];
      esc[i] = ev;
      r1[j] = ev;
      const bool on = (av == 1.0f);
      msk |= (unsigned)on << i;
      m_loc = fmaxf(m_loc, on ? ev : NEG_SENT);
    }
    __builtin_nontemporal_store(r1, (f32x4*)(o1 + c));  // early, no barrier dep
  }

  // ---- Phase 1: block max (plain fmax butterfly; exp not on this path) ----
#pragma unroll
  for (int off = 32; off >= 1; off >>= 1)
    m_loc = fmaxf(m_loc, __shfl_xor(m_loc, off));

  __shared__ float sm[4], ss[4];
  if (lane == 0) sm[wave] = m_loc;
  __syncthreads();
  const float M = fmaxf(fmaxf(sm[0], sm[1]), fmaxf(sm[2], sm[3]));

  // ---- Phase 2: exp once per element (in-place over esc), sum butterfly ----
  float s = 0.0f;
#pragma unroll
  for (int i = 0; i < EPT; ++i) {
    const float pe = ((msk >> i) & 1u) ? __expf(esc[i] - M) : 0.0f;
    esc[i] = pe;   // p overlays esc: o1 already written
    s += pe;
  }
#pragma unroll
  for (int off = 32; off >= 1; off >>= 1)
    s += __shfl_xor(s, off);
  if (lane == 0) ss[wave] = s;
  __syncthreads();
  const float S = (ss[0] + ss[1]) + (ss[2] + ss[3]);
  const float inv = 1.0f / S;

  // ---- Softmax store (nontemporal: never re-read) ----
#pragma unroll
  for (int k = 0; k < 4; ++k) {
    const int c = k * (BLOCK * 4) + tid * 4;
    f32x4 r0;
#pragma unroll
    for (int j = 0; j < 4; ++j) r0[j] = esc[4 * k + j] * inv;
    __builtin_nontemporal_store(r0, (f32x4*)(o0 + c));
  }
}

extern "C" void kernel_launch(void* const* d_in, const int* in_sizes, int n_in,
                              void* d_out, int out_size, void* d_ws, size_t ws_size,
                              hipStream_t stream) {
  const float* e    = (const float*)d_in[0];
  const float* diag = (const float*)d_in[1];
  float* out        = (float*)d_out;
  masked_softmax_kernel<<<NROWS, BLOCK, 0, stream>>>(e, diag, out);
}